// Round 6
// baseline (1197.615 us; speedup 1.0000x reference)
//
#include <hip/hip_runtime.h>
#include <math.h>

typedef _Float16 half_t;
typedef __attribute__((ext_vector_type(8))) _Float16 f16x8;
typedef __attribute__((ext_vector_type(4))) _Float16 f16x4;
typedef __attribute__((ext_vector_type(4))) float f32x4;

#define MFMA16(a, b, c) __builtin_amdgcn_mfma_f32_16x16x32_f16((a), (b), (c), 0, 0, 0)

constexpr int Bc = 4, NQ = 2048, NKC = 2048, CC = 1024, NHD = 16, HDIM = 64;

__device__ __forceinline__ void async_copy16(half_t* lds, const half_t* g) {
  __builtin_amdgcn_global_load_lds(
      (const __attribute__((address_space(1))) unsigned*)g,
      (__attribute__((address_space(3))) unsigned*)lds, 16, 0, 0);
}

// exact numpy-fp16 rope pair: out[o0] = t1*c - t2*s ; out[o1] = t2*c + t1*s
__device__ __forceinline__ void rope_pair(float a1, float a2, float ang,
                                          half_t* out, size_t o0, size_t o1) {
#pragma clang fp contract(off)
  const half_t hc = (half_t)cosf(ang);
  const half_t hs = (half_t)sinf(ang);
  const half_t t1 = (half_t)a1;
  const half_t t2 = (half_t)a2;
  const half_t p1 = t1 * hc;
  const half_t p2 = t2 * hs;
  const half_t p3 = t2 * hc;
  const half_t p4 = t1 * hs;
  out[o0] = p1 - p2;
  out[o1] = p3 + p4;
}

// ---------------------------------------------------------------------------
// weights fp32 -> fp16 (one batched launch, 4 matrices)
// ---------------------------------------------------------------------------
__global__ __launch_bounds__(256) void cvtW(const float* __restrict__ s0,
                                            const float* __restrict__ s1,
                                            const float* __restrict__ s2,
                                            const float* __restrict__ s3,
                                            half_t* __restrict__ dst) {
  const int y = blockIdx.y;
  const float* src = (y == 0) ? s0 : (y == 1) ? s1 : (y == 2) ? s2 : s3;
  const int i = blockIdx.x * 256 + threadIdx.x;
  const f32x4 a = ((const f32x4*)src)[2 * i];
  const f32x4 b = ((const f32x4*)src)[2 * i + 1];
  f16x8 h;
#pragma unroll
  for (int j = 0; j < 4; ++j) { h[j] = (half_t)a[j]; h[4 + j] = (half_t)b[j]; }
  ((f16x8*)(dst + (size_t)y * CC * CC))[i] = h;
}

// ---------------------------------------------------------------------------
// GEMM out[m][n] = sum_k X[m][k]*W[n][k]. 128x128 tile, BK=32, XCD swizzle.
// QKV: fp32 X (cvt in staging, next-tile register prefetch), fused RoPE2D
//      epilogue for z<2, fp16 out. O: fp16 X via global_load_lds, fp32+bias.
// ---------------------------------------------------------------------------
template <bool QKV>
__global__ __launch_bounds__(256) void gemm_k(const float* __restrict__ X0,
                                              const float* __restrict__ X1,
                                              const float* __restrict__ X2,
                                              const half_t* __restrict__ Xh,
                                              const half_t* __restrict__ W16,
                                              half_t* __restrict__ o0,
                                              half_t* __restrict__ o1,
                                              half_t* __restrict__ o2,
                                              float* __restrict__ outf,
                                              const float* __restrict__ bias,
                                              const int* __restrict__ qpos,
                                              const int* __restrict__ kpos) {
  __shared__ half_t As[128 * 32];
  __shared__ half_t Bs[128 * 32];
  const int tid = threadIdx.x, wave = tid >> 6, lane = tid & 63;
  const int quad = lane >> 4, l16 = lane & 15;
  const int z = QKV ? blockIdx.z : 3;
  const int idx = blockIdx.y * 8 + blockIdx.x;   // 0..511
  const int rb = (idx & 7) | ((idx >> 6) << 3);  // row-block 0..63
  const int cb = (idx >> 3) & 7;                 // col-block 0..7
  const int m0 = rb * 128, n0 = cb * 128;
  const int mw = (wave >> 1) * 64, nw = (wave & 1) * 64;

  const float* Xf = QKV ? (z == 0 ? X0 : z == 1 ? X1 : X2) : nullptr;
  const half_t* Wz = W16 + (size_t)z * CC * CC;

  const int arow = (lane >> 2), acol = (lane & 3) * 8;  // async staging map
  const int srow = tid >> 1, sc16 = (tid & 1) * 16;     // fp32-A staging map

  f32x4 acc[4][4] = {};
  f32x4 xr[4];
  const float* xrow = QKV ? (Xf + (size_t)(m0 + srow) * CC + sc16) : nullptr;
  if constexpr (QKV) {
#pragma unroll
    for (int j = 0; j < 4; ++j) xr[j] = *(const f32x4*)(xrow + 4 * j);
  }

  for (int k0 = 0; k0 < CC; k0 += 32) {
    __syncthreads();
    if constexpr (QKV) {
      f16x8 h0, h1;
#pragma unroll
      for (int j = 0; j < 4; ++j) {
        h0[j] = (half_t)xr[0][j]; h0[4 + j] = (half_t)xr[1][j];
        h1[j] = (half_t)xr[2][j]; h1[4 + j] = (half_t)xr[3][j];
      }
      *(f16x8*)&As[srow * 32 + sc16]     = h0;
      *(f16x8*)&As[srow * 32 + sc16 + 8] = h1;
    } else {
#pragma unroll
      for (int c = 0; c < 2; ++c) {
        const int br = (wave * 2 + c) * 16;
        async_copy16(&As[br * 32], Xh + (size_t)(m0 + br + arow) * CC + k0 + acol);
      }
    }
#pragma unroll
    for (int c = 0; c < 2; ++c) {
      const int br = (wave * 2 + c) * 16;
      async_copy16(&Bs[br * 32], Wz + (size_t)(n0 + br + arow) * CC + k0 + acol);
    }
    __syncthreads();

    if (QKV && k0 + 32 < CC) {  // prefetch next A tile (overlaps MFMA below)
#pragma unroll
      for (int j = 0; j < 4; ++j) xr[j] = *(const f32x4*)(xrow + k0 + 32 + 4 * j);
    }

    f16x8 af[4], bf[4];
#pragma unroll
    for (int mi = 0; mi < 4; ++mi) af[mi] = *(const f16x8*)&As[(mw + mi * 16 + l16) * 32 + quad * 8];
#pragma unroll
    for (int ni = 0; ni < 4; ++ni) bf[ni] = *(const f16x8*)&Bs[(nw + ni * 16 + l16) * 32 + quad * 8];
#pragma unroll
    for (int mi = 0; mi < 4; ++mi)
#pragma unroll
      for (int ni = 0; ni < 4; ++ni) acc[mi][ni] = MFMA16(af[mi], bf[ni], acc[mi][ni]);
  }

  if constexpr (QKV) {
    half_t* out16 = z == 0 ? o0 : z == 1 ? o1 : o2;
    if (z < 2) {
      // fused RoPE2D: within head, channel w = ni*16+l16; ni pairs (0,1)=y, (2,3)=x
      const int* pos = (z == 0) ? qpos : kpos;
      const float invf = __builtin_amdgcn_exp2f((float)l16 * -0.41524100904865773f);
#pragma unroll
      for (int mi = 0; mi < 4; ++mi)
#pragma unroll
        for (int r = 0; r < 4; ++r) {
          const int row = m0 + mw + mi * 16 + quad * 4 + r;
          const float py = (float)pos[2 * row];
          const float px = (float)pos[2 * row + 1];
          const size_t base = (size_t)row * CC + n0 + nw + l16;
          rope_pair(acc[mi][0][r], acc[mi][1][r], py * invf, out16, base, base + 16);
          rope_pair(acc[mi][2][r], acc[mi][3][r], px * invf, out16, base + 32, base + 48);
        }
    } else {
#pragma unroll
      for (int mi = 0; mi < 4; ++mi)
#pragma unroll
        for (int ni = 0; ni < 4; ++ni)
#pragma unroll
          for (int r = 0; r < 4; ++r)
            out16[(size_t)(m0 + mw + mi * 16 + quad * 4 + r) * CC + n0 + nw + ni * 16 + l16] =
                (half_t)acc[mi][ni][r];
    }
  } else {
#pragma unroll
    for (int mi = 0; mi < 4; ++mi)
#pragma unroll
      for (int ni = 0; ni < 4; ++ni)
#pragma unroll
        for (int r = 0; r < 4; ++r) {
          const int col = n0 + nw + ni * 16 + l16;
          outf[(size_t)(m0 + mw + mi * 16 + quad * 4 + r) * CC + col] = acc[mi][ni][r] + bias[col];
        }
  }
}

// ---------------------------------------------------------------------------
// Flash attention v3, S^T formulation, KT=64, all LDS in MFMA fragment order:
//   Ksf: (key,d) at (key>>4)*1024 + ((d>>3)*16 + (key&15))*8 + (d&7)
//   Vsf: (key,d) at (d>>4)*1024 + ((key>>3)*16 + (d&15))*8 + (key&7)
//   Pt : (q,key)  at (key>>5)*512 + (((key>>3)&3)*16 + q)*8 + (key&7)
// All frag reads are base + lane*16B (conflict-free); Pt writes packed b64
// (2-way, free). Max-free softmax, deferred row sums. Register prefetch of
// next K/V tile. XCD swizzle: blocks of one (b,h) share an XCD.
// ---------------------------------------------------------------------------
__global__ __launch_bounds__(256) void attn_kernel(const half_t* __restrict__ q16,
                                                   const half_t* __restrict__ k16,
                                                   const half_t* __restrict__ v16,
                                                   half_t* __restrict__ x16) {
  __shared__ half_t Ksf[4096];      // 8 KB
  __shared__ half_t Vsf[4096];      // 8 KB
  __shared__ half_t Pt[4][2][1024]; // 16 KB, wave-private [wave][mi]
  const int tid = threadIdx.x, wave = tid >> 6, lane = tid & 63;
  const int quad = lane >> 4, l16 = lane & 15;
  const int bx = blockIdx.x;
  const int bh = bx & 63, qblk = bx >> 6;
  const int h = bh & 15, b = bh >> 4;
  const f32x4 zero = {0.f, 0.f, 0.f, 0.f};

  // Q fragments (B-operand): [n=q=l16][k=d=kc*32+quad*8+j]
  f16x8 qa[2][2];
  {
    const half_t* qbase =
        q16 + (size_t)(b * NQ + qblk * 128 + wave * 32 + l16) * CC + h * HDIM + quad * 8;
#pragma unroll
    for (int mi = 0; mi < 2; ++mi)
#pragma unroll
      for (int kc = 0; kc < 2; ++kc)
        qa[mi][kc] = *(const f16x8*)(qbase + (size_t)mi * 16 * CC + kc * 32);
  }

  f32x4 o[2][4] = {};
  float lp[2] = {0.f, 0.f};

  // K staging: key-major (write conflict-free): key = tid&63, d0 = (tid>>6)*16
  const int kkey = tid & 63, kd0 = (tid >> 6) * 16;
  const half_t* kptr = k16 + (size_t)(b * NKC + kkey) * CC + h * HDIM + kd0;
  int kdst[2];
#pragma unroll
  for (int c = 0; c < 2; ++c)
    kdst[c] = (kkey >> 4) * 1024 + (((kd0 >> 3) + c) * 16 + (kkey & 15)) * 8;

  // V staging: d-pair-major: d pair vd..vd+1, keys vk0..vk0+7
  const int vd = 2 * (tid & 31), vk0 = (tid >> 5) * 8;
  const half_t* vptr = v16 + (size_t)(b * NKC + vk0) * CC + h * HDIM + vd;
  int vdst[2];
#pragma unroll
  for (int e = 0; e < 2; ++e)
    vdst[e] = ((vd + e) >> 4) * 1024 + ((vk0 >> 3) * 16 + ((vd + e) & 15)) * 8;

  f16x8 kr[2];
  unsigned vr[8];
  kr[0] = *(const f16x8*)kptr;
  kr[1] = *(const f16x8*)(kptr + 8);
#pragma unroll
  for (int j = 0; j < 8; ++j) vr[j] = *(const unsigned*)(vptr + (size_t)j * CC);

  for (int kt = 0; kt < NKC; kt += 64) {
    __syncthreads();
    *(f16x8*)&Ksf[kdst[0]] = kr[0];
    *(f16x8*)&Ksf[kdst[1]] = kr[1];
    {
      f16x8 we0, we1;
#pragma unroll
      for (int j = 0; j < 8; ++j) {
        union { unsigned u; half_t h2[2]; } x;
        x.u = vr[j];
        we0[j] = x.h2[0];
        we1[j] = x.h2[1];
      }
      *(f16x8*)&Vsf[vdst[0]] = we0;
      *(f16x8*)&Vsf[vdst[1]] = we1;
    }
    __syncthreads();

    if (kt + 64 < NKC) {  // register prefetch next tile (overlaps compute)
      const half_t* kn = kptr + (size_t)(kt + 64) * CC;
      const half_t* vn = vptr + (size_t)(kt + 64) * CC;
      kr[0] = *(const f16x8*)kn;
      kr[1] = *(const f16x8*)(kn + 8);
#pragma unroll
      for (int j = 0; j < 8; ++j) vr[j] = *(const unsigned*)(vn + (size_t)j * CC);
    }

    // S^T = K.Q^T per 16-key block; exp; packed P^T writes
#pragma unroll
    for (int nbl = 0; nbl < 4; ++nbl) {
      const f16x8 kb0 = *(const f16x8*)&Ksf[nbl * 1024 + lane * 8];
      const f16x8 kb1 = *(const f16x8*)&Ksf[nbl * 1024 + 512 + lane * 8];
      const int pwoff =
          (nbl >> 1) * 512 + (((2 * nbl) & 3) + (quad >> 1)) * 128 + l16 * 8 + (quad & 1) * 4;
#pragma unroll
      for (int mi = 0; mi < 2; ++mi) {
        const f32x4 t0 = MFMA16(kb0, qa[mi][0], zero);
        const f32x4 s  = MFMA16(kb1, qa[mi][1], t0);
        f16x4 pk;
#pragma unroll
        for (int r = 0; r < 4; ++r) {
          const float p = __builtin_amdgcn_exp2f(s[r] * 0.18033688011112042f);
          lp[mi] += p;
          pk[r] = (half_t)p;
        }
        *(f16x4*)&Pt[wave][mi][pwoff] = pk;
      }
    }

    // O^T += V^T . P^T
#pragma unroll
    for (int kk = 0; kk < 2; ++kk) {
      const f16x8 pb0 = *(const f16x8*)&Pt[wave][0][kk * 512 + lane * 8];
      const f16x8 pb1 = *(const f16x8*)&Pt[wave][1][kk * 512 + lane * 8];
#pragma unroll
      for (int md = 0; md < 4; ++md) {
        const f16x8 va = *(const f16x8*)&Vsf[md * 1024 + kk * 512 + lane * 8];
        o[0][md] = MFMA16(va, pb0, o[0][md]);
        o[1][md] = MFMA16(va, pb1, o[1][md]);
      }
    }
  }

#pragma unroll
  for (int mi = 0; mi < 2; ++mi) {
    float rs = lp[mi];
    rs += __shfl_xor(rs, 16);
    rs += __shfl_xor(rs, 32);
    const float inv = 1.f / rs;
    const size_t qrow = (size_t)(b * NQ + qblk * 128 + wave * 32 + mi * 16 + l16);
#pragma unroll
    for (int md = 0; md < 4; ++md) {
      f16x4 pk;
#pragma unroll
      for (int r = 0; r < 4; ++r) pk[r] = (half_t)(o[mi][md][r] * inv);
      *(f16x4*)&x16[qrow * CC + h * HDIM + md * 16 + quad * 4] = pk;
    }
  }
}

// ---------------------------------------------------------------------------
extern "C" void kernel_launch(void* const* d_in, const int* in_sizes, int n_in,
                              void* d_out, int out_size, void* d_ws, size_t ws_size,
                              hipStream_t stream) {
  const float* query = (const float*)d_in[0];
  const float* key   = (const float*)d_in[1];
  const float* value = (const float*)d_in[2];
  const int*   qpos  = (const int*)d_in[3];
  const int*   kpos  = (const int*)d_in[4];
  const float* Wq = (const float*)d_in[5];
  const float* Wk = (const float*)d_in[6];
  const float* Wv = (const float*)d_in[7];
  const float* Wo = (const float*)d_in[8];
  const float* bo = (const float*)d_in[9];
  float* out = (float*)d_out;

  const size_t NT = (size_t)Bc * NQ * CC;
  half_t* q16 = (half_t*)d_ws;
  half_t* k16 = q16 + NT;
  half_t* v16 = k16 + NT;
  half_t* x16 = v16 + NT;
  half_t* W16 = x16 + NT;

  cvtW<<<dim3((CC * CC) / 8 / 256, 4), 256, 0, stream>>>(Wq, Wk, Wv, Wo, W16);

  gemm_k<true><<<dim3(8, 64, 3), 256, 0, stream>>>(query, key, value, nullptr, W16,
                                                   q16, k16, v16, nullptr, nullptr,
                                                   qpos, kpos);

  attn_kernel<<<dim3(NQ / 128 * NHD * Bc), 256, 0, stream>>>(q16, k16, v16, x16);

  gemm_k<false><<<dim3(8, 64), 256, 0, stream>>>(nullptr, nullptr, nullptr, x16, W16,
                                                 nullptr, nullptr, nullptr, out, bo,
                                                 nullptr, nullptr);
}